// Round 3
// baseline (476.337 us; speedup 1.0000x reference)
//
#include <hip/hip_runtime.h>
#include <math.h>

// PointPWC multi-scale loss. B=2, scales N={8192,4096,2048,1024}.
// Inputs (B,3,N) fp32 channel-major. Output: single fp32 scalar.
//
// R11: wave-granular dynamic scheduling. R9 (LDS broadcast) and R10 (SMEM
// broadcast) both measured 267.5us -> the bound is NOT candidate delivery;
// it is dispatch quantization: 1360 equal blocks on 1024 block slots = 2
// rounds (VALU ideal ~134us, measured 267 = 2.0x, occupancy 64% = 2-round
// fill average). Fix: persistent 8192 waves pop 10880 uniform wave-tasks
// (64 queries x 1024-cand chunk) from an atomic queue; no LDS, no
// barriers. Partial top-K packed keys -> workspace; k_epi_a/b merge
// (exact: keys totally ordered, union covers) + epilogues. Pass D partial
// mins via atomicMin (uint order == float order for d>=0). Distance core
// uses float2 ext-vectors (v_pk_* candidates); per-half IEEE identical.

#define UNIT 1024
#define NTOT 15360
#define MASKC 0xFFFFE000u
#define PB 340
#define BLOCK 512
#define NTASKS 10880   // 4 passes x 2720
#define TOTS 174080    // total partial-list slots per pass-array

typedef unsigned int uint;
typedef __attribute__((ext_vector_type(8))) float f8;
typedef __attribute__((ext_vector_type(2))) float f2;

struct Params {
  const float* pc1[4];
  const float* pc2[4];
  const float* fl[4];
  float4* cv2;   // [B][NTOT]
  float4* cvw;   // [B][NTOT]
  float* k0;     // [10][TOTS] partial keys, pass A
  float* k1;     // [10][TOTS] partial keys, pass B
  float* k3;     // [5][TOTS]  partial keys, pass C
  uint* d2u;     // [2*NTOT]   partial mins, pass D
  uint* cnt;     // task queue counter
  float* keys;   // fallback-path keys [5][2*NTOT]
  float* out;
};

// ---------- shared helpers ----------

__device__ __forceinline__ float wave_sum(float v) {
  #pragma unroll
  for (int o = 32; o; o >>= 1) v += __shfl_down(v, o, 64);
  return v;
}

template <int K>
__device__ __forceinline__ void key_insert(float (&kd)[K], float kf) {
  #pragma unroll
  for (int m = K - 1; m >= 1; --m)
    kd[m] = __builtin_amdgcn_fmed3f(kf, kd[m - 1], kd[m]);
  kd[0] = fminf(kd[0], kf);
}

template <int K>
__device__ __forceinline__ void merge_pair(float (&a)[K], const float (&b)[K]) {
  #pragma unroll
  for (int m = 0; m < K; ++m) key_insert<K>(a, b[m]);
}

// Wave-uniform broadcast of 8 candidates (3 planes) into SGPRs. Loads +
// waitcnt fused in ONE asm block (SMEM completes out-of-order).
__device__ __forceinline__ void sload3(const float* px, const float* py,
                                       const float* pz, int boff,
                                       f8& x, f8& y, f8& z) {
  asm volatile(
      "s_load_dwordx8 %0, %3, %6\n\t"
      "s_load_dwordx8 %1, %4, %6\n\t"
      "s_load_dwordx8 %2, %5, %6\n\t"
      "s_waitcnt lgkmcnt(0)"
      : "=&s"(x), "=&s"(y), "=&s"(z)
      : "s"(px), "s"(py), "s"(pz), "s"(boff));
}

__device__ __forceinline__ void sload6(const float* px, const float* py,
                                       const float* pz, const float* fx,
                                       const float* fy, const float* fz,
                                       int boff, f8& x, f8& y, f8& z,
                                       f8& u, f8& v, f8& w) {
  asm volatile(
      "s_load_dwordx8 %0, %6, %12\n\t"
      "s_load_dwordx8 %1, %7, %12\n\t"
      "s_load_dwordx8 %2, %8, %12\n\t"
      "s_load_dwordx8 %3, %9, %12\n\t"
      "s_load_dwordx8 %4, %10, %12\n\t"
      "s_load_dwordx8 %5, %11, %12\n\t"
      "s_waitcnt lgkmcnt(0)"
      : "=&s"(x), "=&s"(y), "=&s"(z), "=&s"(u), "=&s"(v), "=&s"(w)
      : "s"(px), "s"(py), "s"(pz), "s"(fx), "s"(fy), "s"(fz), "s"(boff));
}

// Top-K scan over [lo, lo+UNIT); candidates from SGPRs, f2 packed dist
// (per-half IEEE sub/fma == scalar: bit-identical keys). Two chains.
template <int K>
__device__ void scan_k(const float* px, const float* py, const float* pz,
                       int lo, float ax, float ay, float az,
                       float (&a)[K], float (&b)[K]) {
  f2 qx = {ax, ax}, qy = {ay, ay}, qz = {az, az};
  #pragma unroll 1
  for (int c0 = 0; c0 < UNIT; c0 += 8) {
    f8 xs, ys, zs;
    sload3(px, py, pz, (lo + c0) * 4, xs, ys, zs);
    #pragma unroll
    for (int t = 0; t < 8; t += 2) {
      f2 dx = f2{xs[t], xs[t + 1]} - qx;
      f2 dy = f2{ys[t], ys[t + 1]} - qy;
      f2 dz = f2{zs[t], zs[t + 1]} - qz;
      f2 d = __builtin_elementwise_fma(
          dx, dx, __builtin_elementwise_fma(dy, dy, dz * dz));
      uint i0 = (uint)(lo + c0 + t);
      key_insert<K>(a, __uint_as_float((__float_as_uint(d.x) & MASKC) | i0));
      key_insert<K>(b,
                    __uint_as_float((__float_as_uint(d.y) & MASKC) | (i0 + 1)));
    }
  }
}

// Pass-D scan: candidates = p1+fl (scalar, exact R10 rounding), min only.
__device__ void scan_w(const float* px, const float* py, const float* pz,
                       const float* fx, const float* fy, const float* fz,
                       int lo, float ax, float ay, float az,
                       float (&a)[1], float (&b)[1]) {
  #pragma unroll 1
  for (int c0 = 0; c0 < UNIT; c0 += 8) {
    f8 xs, ys, zs, us, vs, ws;
    sload6(px, py, pz, fx, fy, fz, (lo + c0) * 4, xs, ys, zs, us, vs, ws);
    #pragma unroll
    for (int t = 0; t < 8; t += 2) {
      float cxa = xs[t] + us[t], cya = ys[t] + vs[t], cza = zs[t] + ws[t];
      float dxa = cxa - ax, dya = cya - ay, dza = cza - az;
      float dA = fmaf(dxa, dxa, fmaf(dya, dya, dza * dza));
      float cxb = xs[t + 1] + us[t + 1], cyb = ys[t + 1] + vs[t + 1],
            czb = zs[t + 1] + ws[t + 1];
      float dxb = cxb - ax, dyb = cyb - ay, dzb = czb - az;
      float dB = fmaf(dxb, dxb, fmaf(dyb, dyb, dzb * dzb));
      a[0] = fminf(a[0], dA);
      b[0] = fminf(b[0], dB);
    }
  }
}

// ---------- new path: dynamic wave tasks ----------

__global__ __launch_bounds__(256) void k_init(Params P) {
  int t = blockIdx.x * 256 + threadIdx.x;
  if (t == 0) { P.out[0] = 0.f; *P.cnt = 0u; }
  if (t < 2 * NTOT) P.d2u[t] = 0x7F7FFFFFu;   // FLT_MAX bits
}

// Task id t: pass p = t/2720 in order {A, B, C, D} (heavy->light).
// Within pass, u -> (scale s, part, qgroup g): s0 first (uniform sizes
// per pass keep the initial 8192 blind grabs balanced).
__global__ __launch_bounds__(256, 8) void k_scan(Params P) {
  int lane = threadIdx.x & 63;
  for (;;) {
    uint t;
    if (lane == 0) t = atomicAdd(P.cnt, 1u);
    t = (uint)__builtin_amdgcn_readfirstlane(__shfl((int)t, 0, 64));
    if (t >= NTASKS) return;
    int p = t / 2720, u = t % 2720;
    int s, part, g;
    if (u < 2048)      { s = 0; part = u & 7; g = u >> 3; }
    else if (u < 2560) { s = 1; u -= 2048; part = u & 3; g = u >> 2; }
    else if (u < 2688) { s = 2; u -= 2560; part = u & 1; g = u >> 1; }
    else               { s = 3; u -= 2688; part = 0; g = u; }
    int gpb = 128 >> s;
    int b = g >> (7 - s), qg = g & (gpb - 1);
    int N = 8192 >> s, i = qg * 64 + lane, lo = part << 10;
    int off = 16384 - (16384 >> s);
    int qid = b * NTOT + off + i;
    int sb = (s == 0) ? 0 : (s == 1) ? 131072 : (s == 2) ? 163840 : 172032;
    int slot = sb + part * 2 * N + b * N + i;

    if (p == 0) {          // A: p2 self top-10 partial
      const float* p2 = P.pc2[s] + b * 3 * N;
      float ax = p2[i], ay = p2[N + i], az = p2[2 * N + i];
      float a[10], bb[10];
      #pragma unroll
      for (int m = 0; m < 10; ++m) { a[m] = 3.0e38f; bb[m] = 3.0e38f; }
      scan_k<10>(p2, p2 + N, p2 + 2 * N, lo, ax, ay, az, a, bb);
      merge_pair<10>(a, bb);
      #pragma unroll
      for (int m = 0; m < 10; ++m) P.k0[m * TOTS + slot] = a[m];
    } else if (p == 1) {   // B: p1 self top-10 partial
      const float* p1 = P.pc1[s] + b * 3 * N;
      float ax = p1[i], ay = p1[N + i], az = p1[2 * N + i];
      float a[10], bb[10];
      #pragma unroll
      for (int m = 0; m < 10; ++m) { a[m] = 3.0e38f; bb[m] = 3.0e38f; }
      scan_k<10>(p1, p1 + N, p1 + 2 * N, lo, ax, ay, az, a, bb);
      merge_pair<10>(a, bb);
      #pragma unroll
      for (int m = 0; m < 10; ++m) P.k1[m * TOTS + slot] = a[m];
    } else if (p == 2) {   // C: warp -> p2 top-5 partial
      const float* p1 = P.pc1[s] + b * 3 * N;
      const float* fl = P.fl[s] + b * 3 * N;
      const float* p2 = P.pc2[s] + b * 3 * N;
      float ax = p1[i] + fl[i], ay = p1[N + i] + fl[N + i],
            az = p1[2 * N + i] + fl[2 * N + i];
      float a[5], bb[5];
      #pragma unroll
      for (int m = 0; m < 5; ++m) { a[m] = 3.0e38f; bb[m] = 3.0e38f; }
      scan_k<5>(p2, p2 + N, p2 + 2 * N, lo, ax, ay, az, a, bb);
      merge_pair<5>(a, bb);
      #pragma unroll
      for (int m = 0; m < 5; ++m) P.k3[m * TOTS + slot] = a[m];
    } else {               // D: p2 -> warp min partial
      const float* p1 = P.pc1[s] + b * 3 * N;
      const float* fl = P.fl[s] + b * 3 * N;
      const float* p2 = P.pc2[s] + b * 3 * N;
      float ax = p2[i], ay = p2[N + i], az = p2[2 * N + i];
      float a[1], bb[1];
      a[0] = 3.0e38f; bb[0] = 3.0e38f;
      scan_w(p1, p1 + N, p1 + 2 * N, fl, fl + N, fl + 2 * N,
             lo, ax, ay, az, a, bb);
      atomicMin(P.d2u + qid, __float_as_uint(fminf(a[0], bb[0])));
    }
  }
}

// Merge A/B partials -> cv2, cvw + smooth; accumulate dist2. 30720 lanes.
__global__ __launch_bounds__(256) void k_epi_a(Params P) {
  int t = blockIdx.x * 256 + threadIdx.x;
  int bq = t >= NTOT;
  int r = t - bq * NTOT;
  int s, i;
  if (r < 8192)       { s = 0; i = r; }
  else if (r < 12288) { s = 1; i = r - 8192; }
  else if (r < 14336) { s = 2; i = r - 12288; }
  else                { s = 3; i = r - 14336; }
  int N = 8192 >> s;
  int off = 16384 - (16384 >> s);
  float alpha = 0.02f * (float)(1 << s);
  int sb = (s == 0) ? 0 : (s == 1) ? 131072 : (s == 2) ? 163840 : 172032;
  int slot0 = sb + bq * N + i, stride = 2 * N, parts = 8 >> s;
  const float inv9 = 1.f / 9.f;

  // A: p2 self-KNN -> cv2
  const float* p2 = P.pc2[s] + bq * 3 * N;
  {
    float ax = p2[i], ay = p2[N + i], az = p2[2 * N + i];
    float a[10];
    #pragma unroll
    for (int m = 0; m < 10; ++m) a[m] = 3.0e38f;
    for (int part = 0; part < parts; ++part)
      #pragma unroll
      for (int m = 0; m < 10; ++m)
        key_insert<10>(a, P.k0[m * TOTS + slot0 + part * stride]);
    float sx = 0.f, sy = 0.f, sz = 0.f;
    #pragma unroll
    for (int m = 0; m < 10; ++m) {
      int j = (int)(__float_as_uint(a[m]) & 0x1FFFu);
      sx += p2[j]; sy += p2[N + j]; sz += p2[2 * N + j];
    }
    P.cv2[bq * NTOT + off + i] = make_float4((sx - 10.f * ax) * inv9,
                                             (sy - 10.f * ay) * inv9,
                                             (sz - 10.f * az) * inv9, 0.f);
  }

  // B: p1 self-KNN -> cvw + smoothness
  {
    const float* p1 = P.pc1[s] + bq * 3 * N;
    const float* fl = P.fl[s] + bq * 3 * N;
    float ax = p1[i], ay = p1[N + i], az = p1[2 * N + i];
    float a[10];
    #pragma unroll
    for (int m = 0; m < 10; ++m) a[m] = 3.0e38f;
    for (int part = 0; part < parts; ++part)
      #pragma unroll
      for (int m = 0; m < 10; ++m)
        key_insert<10>(a, P.k1[m * TOTS + slot0 + part * stride]);
    float fix = fl[i], fiy = fl[N + i], fiz = fl[2 * N + i];
    float wix = ax + fix, wiy = ay + fiy, wiz = az + fiz;
    float sx = 0.f, sy = 0.f, sz = 0.f, smooth = 0.f;
    float dmax = -1.f, worst = 0.f;
    #pragma unroll
    for (int m = 0; m < 10; ++m) {
      int j = (int)(__float_as_uint(a[m]) & 0x1FFFu);
      float px = p1[j], py = p1[N + j], pz = p1[2 * N + j];
      float flx = fl[j], fly = fl[N + j], flz = fl[2 * N + j];
      sx += px + flx; sy += py + fly; sz += pz + flz;
      float ddx = px - ax, ddy = py - ay, ddz = pz - az;
      float d = fmaf(ddx, ddx, fmaf(ddy, ddy, ddz * ddz));  // exact
      float gx = flx - fix, gy = fly - fiy, gz = flz - fiz;
      float term = sqrtf(fmaf(gx, gx, fmaf(gy, gy, gz * gz)));
      smooth += term;
      if (d > dmax) { dmax = d; worst = term; }  // drop farthest (k9)
    }
    smooth -= worst;
    P.cvw[bq * NTOT + off + i] = make_float4((sx - 10.f * wix) * inv9,
                                             (sy - 10.f * wiy) * inv9,
                                             (sz - 10.f * wiz) * inv9, 0.f);
    float ssum = wave_sum(smooth * (1.f / 8.f));
    if ((threadIdx.x & 63) == 0) atomicAdd(P.out, alpha * 0.5f * ssum);
  }

  // D: dist2 accumulate
  {
    float dm = __uint_as_float(P.d2u[t]);
    float msum = wave_sum(dm);
    if ((threadIdx.x & 63) == 0) atomicAdd(P.out, alpha * 0.5f * msum);
  }
}

// Merge C partials -> top-5; dist1 + inverse-distance cv2 interp -> curv.
__global__ __launch_bounds__(256) void k_epi_b(Params P) {
  int t = blockIdx.x * 256 + threadIdx.x;
  int bq = t >= NTOT;
  int r = t - bq * NTOT;
  int s, i;
  if (r < 8192)       { s = 0; i = r; }
  else if (r < 12288) { s = 1; i = r - 8192; }
  else if (r < 14336) { s = 2; i = r - 12288; }
  else                { s = 3; i = r - 14336; }
  int N = 8192 >> s;
  int off = 16384 - (16384 >> s);
  float alpha = 0.02f * (float)(1 << s);
  int sb = (s == 0) ? 0 : (s == 1) ? 131072 : (s == 2) ? 163840 : 172032;
  int slot0 = sb + bq * N + i, stride = 2 * N, parts = 8 >> s;
  const float* p1 = P.pc1[s] + bq * 3 * N;
  const float* fl = P.fl[s] + bq * 3 * N;
  const float* p2 = P.pc2[s] + bq * 3 * N;
  float ax = p1[i] + fl[i], ay = p1[N + i] + fl[N + i],
        az = p1[2 * N + i] + fl[2 * N + i];
  float a[5];
  #pragma unroll
  for (int m = 0; m < 5; ++m) a[m] = 3.0e38f;
  for (int part = 0; part < parts; ++part)
    #pragma unroll
    for (int m = 0; m < 5; ++m)
      key_insert<5>(a, P.k3[m * TOTS + slot0 + part * stride]);
  float dist1 = 3.0e38f, wsum = 0.f, ix = 0.f, iy = 0.f, iz = 0.f;
  #pragma unroll
  for (int m = 0; m < 5; ++m) {
    int j = (int)(__float_as_uint(a[m]) & 0x1FFFu);
    float px = p2[j], py = p2[N + j], pz = p2[2 * N + j];
    float ddx = px - ax, ddy = py - ay, ddz = pz - az;
    float d = fmaf(ddx, ddx, fmaf(ddy, ddy, ddz * ddz));  // exact
    dist1 = fminf(dist1, d);
    float w = 1.f / (d + 1e-8f);
    wsum += w;
    float4 cv = P.cv2[bq * NTOT + off + j];
    ix += w * cv.x; iy += w * cv.y; iz += w * cv.z;
  }
  float inv = 1.f / wsum;
  ix *= inv; iy *= inv; iz *= inv;
  float4 cw = P.cvw[bq * NTOT + off + i];
  float ex = ix - cw.x, ey = iy - cw.y, ez = iz - cw.z;
  float curv = fmaf(ex, ex, fmaf(ey, ey, ez * ez));
  float v = wave_sum(dist1 + 0.3f * curv);
  if ((threadIdx.x & 63) == 0) atomicAdd(P.out, alpha * 0.5f * v);
}

// ---------- fallback path (R10, proven) for small ws_size ----------

__device__ __forceinline__ void decode(int r, int wv, int& s, int& b,
                                       int& i0, int& lo, int& N, int& cpw,
                                       int& off, float& alpha) {
  int rr;
  if (r < 256)      { s = 0; rr = r; }
  else if (r < 320) { s = 1; rr = r - 256; }
  else if (r < 336) { s = 2; rr = r - 320; }
  else              { s = 3; rr = r - 336; }
  N = 8192 >> s;
  cpw = 8 >> s;
  int perb = 128 >> (2 * s);
  b = rr >> (7 - 2 * s);
  int chunk = rr & (perb - 1);
  int qg = (chunk << s) + (wv >> (3 - s));
  i0 = qg << 6;
  lo = (wv & (cpw - 1)) << 10;
  off = 16384 - (16384 >> s);
  alpha = 0.02f * (float)(1 << s);
}

template <int K>
__device__ __forceinline__ bool merge_group(float (&a)[K], float* sm,
                                            int tid, int cpw) {
  const int STR = K | 1;
  int q = tid & 63, wv = tid >> 6;
  #pragma unroll
  for (int m = 0; m < K; ++m) sm[(wv * 64 + q) * STR + m] = a[m];
  __syncthreads();
  if (wv & (cpw - 1)) return false;
  for (int w = wv + 1; w < wv + cpw; ++w)
    #pragma unroll
    for (int m = 0; m < K; ++m)
      key_insert<K>(a, sm[(w * 64 + q) * STR + m]);
  return true;
}

__global__ __launch_bounds__(1) void k_zero(float* out) { out[0] = 0.f; }

__global__ __launch_bounds__(BLOCK, 8) void k_fused(Params P) {
  __shared__ float sm[8 * 64 * 11];
  int tid = threadIdx.x, q = tid & 63, wv = tid >> 6;
  int pass = blockIdx.x / PB, r = blockIdx.x % PB;
  int s, b, i0, lo, N, cpw, off; float alpha;
  decode(r, wv, s, b, i0, lo, N, cpw, off, alpha);
  int i = i0 + q;
  int lo_u = __builtin_amdgcn_readfirstlane(lo);

  if (pass == 0) {
    const float* p2 = P.pc2[s] + b * 3 * N;
    float ax = p2[i], ay = p2[N + i], az = p2[2 * N + i];
    float a[10], bb[10];
    #pragma unroll
    for (int m = 0; m < 10; ++m) { a[m] = 3.0e38f; bb[m] = 3.0e38f; }
    scan_k<10>(p2, p2 + N, p2 + 2 * N, lo_u, ax, ay, az, a, bb);
    merge_pair<10>(a, bb);
    if (!merge_group<10>(a, sm, tid, cpw)) return;
    float sx = 0.f, sy = 0.f, sz = 0.f;
    #pragma unroll
    for (int m = 0; m < 10; ++m) {
      int j = (int)(__float_as_uint(a[m]) & 0x1FFFu);
      sx += p2[j]; sy += p2[N + j]; sz += p2[2 * N + j];
    }
    const float inv9 = 1.f / 9.f;
    P.cv2[b * NTOT + off + i] = make_float4((sx - 10.f * ax) * inv9,
                                            (sy - 10.f * ay) * inv9,
                                            (sz - 10.f * az) * inv9, 0.f);
  } else if (pass == 1) {
    const float* p1 = P.pc1[s] + b * 3 * N;
    const float* fl = P.fl[s] + b * 3 * N;
    float ax = p1[i], ay = p1[N + i], az = p1[2 * N + i];
    float a[10], bb[10];
    #pragma unroll
    for (int m = 0; m < 10; ++m) { a[m] = 3.0e38f; bb[m] = 3.0e38f; }
    scan_k<10>(p1, p1 + N, p1 + 2 * N, lo_u, ax, ay, az, a, bb);
    merge_pair<10>(a, bb);
    if (!merge_group<10>(a, sm, tid, cpw)) return;
    float fix = fl[i], fiy = fl[N + i], fiz = fl[2 * N + i];
    float wix = ax + fix, wiy = ay + fiy, wiz = az + fiz;
    float sx = 0.f, sy = 0.f, sz = 0.f, smooth = 0.f;
    float dmax = -1.f, worst = 0.f;
    #pragma unroll
    for (int m = 0; m < 10; ++m) {
      int j = (int)(__float_as_uint(a[m]) & 0x1FFFu);
      float px = p1[j], py = p1[N + j], pz = p1[2 * N + j];
      float flx = fl[j], fly = fl[N + j], flz = fl[2 * N + j];
      sx += px + flx; sy += py + fly; sz += pz + flz;
      float ddx = px - ax, ddy = py - ay, ddz = pz - az;
      float d = fmaf(ddx, ddx, fmaf(ddy, ddy, ddz * ddz));
      float gx = flx - fix, gy = fly - fiy, gz = flz - fiz;
      float term = sqrtf(fmaf(gx, gx, fmaf(gy, gy, gz * gz)));
      smooth += term;
      if (d > dmax) { dmax = d; worst = term; }
    }
    smooth -= worst;
    const float inv9 = 1.f / 9.f;
    P.cvw[b * NTOT + off + i] = make_float4((sx - 10.f * wix) * inv9,
                                            (sy - 10.f * wiy) * inv9,
                                            (sz - 10.f * wiz) * inv9, 0.f);
    float ssum = wave_sum(smooth * (1.f / 8.f));
    if (q == 0) atomicAdd(P.out, alpha * 0.5f * ssum);
  } else if (pass == 2) {
    const float* p1 = P.pc1[s] + b * 3 * N;
    const float* fl = P.fl[s] + b * 3 * N;
    const float* p2 = P.pc2[s] + b * 3 * N;
    float ax = p2[i], ay = p2[N + i], az = p2[2 * N + i];
    float a[1], bb[1];
    a[0] = 3.0e38f; bb[0] = 3.0e38f;
    scan_w(p1, p1 + N, p1 + 2 * N, fl, fl + N, fl + 2 * N,
           lo_u, ax, ay, az, a, bb);
    merge_pair<1>(a, bb);
    if (!merge_group<1>(a, sm, tid, cpw)) return;
    float msum = wave_sum(a[0]);
    if (q == 0) atomicAdd(P.out, alpha * 0.5f * msum);
  } else {
    const float* p1 = P.pc1[s] + b * 3 * N;
    const float* fl = P.fl[s] + b * 3 * N;
    const float* p2 = P.pc2[s] + b * 3 * N;
    float ax = p1[i] + fl[i], ay = p1[N + i] + fl[N + i],
          az = p1[2 * N + i] + fl[2 * N + i];
    float a[5], bb[5];
    #pragma unroll
    for (int m = 0; m < 5; ++m) { a[m] = 3.0e38f; bb[m] = 3.0e38f; }
    scan_k<5>(p2, p2 + N, p2 + 2 * N, lo_u, ax, ay, az, a, bb);
    merge_pair<5>(a, bb);
    if (!merge_group<5>(a, sm, tid, cpw)) return;
    #pragma unroll
    for (int m = 0; m < 5; ++m)
      P.keys[m * (2 * NTOT) + b * NTOT + off + i] = a[m];
  }
}

__global__ __launch_bounds__(256) void k_epi(Params P) {
  int t = blockIdx.x * 256 + threadIdx.x;
  int b = t >= NTOT;
  int r = t - b * NTOT;
  int s, i;
  if (r < 8192)       { s = 0; i = r; }
  else if (r < 12288) { s = 1; i = r - 8192; }
  else if (r < 14336) { s = 2; i = r - 12288; }
  else                { s = 3; i = r - 14336; }
  int N = 8192 >> s;
  int off = 16384 - (16384 >> s);
  float alpha = 0.02f * (float)(1 << s);
  const float* p1 = P.pc1[s] + b * 3 * N;
  const float* fl = P.fl[s] + b * 3 * N;
  const float* p2 = P.pc2[s] + b * 3 * N;
  float ax = p1[i] + fl[i], ay = p1[N + i] + fl[N + i],
        az = p1[2 * N + i] + fl[2 * N + i];
  float dist1 = 3.0e38f, wsum = 0.f, ix = 0.f, iy = 0.f, iz = 0.f;
  #pragma unroll
  for (int m = 0; m < 5; ++m) {
    uint key = __float_as_uint(P.keys[m * (2 * NTOT) + b * NTOT + off + i]);
    int j = (int)(key & 0x1FFFu);
    float px = p2[j], py = p2[N + j], pz = p2[2 * N + j];
    float ddx = px - ax, ddy = py - ay, ddz = pz - az;
    float d = fmaf(ddx, ddx, fmaf(ddy, ddy, ddz * ddz));
    dist1 = fminf(dist1, d);
    float w = 1.f / (d + 1e-8f);
    wsum += w;
    float4 cv = P.cv2[b * NTOT + off + j];
    ix += w * cv.x; iy += w * cv.y; iz += w * cv.z;
  }
  float inv = 1.f / wsum;
  ix *= inv; iy *= inv; iz *= inv;
  float4 cw = P.cvw[b * NTOT + off + i];
  float ex = ix - cw.x, ey = iy - cw.y, ez = iz - cw.z;
  float curv = fmaf(ex, ex, fmaf(ey, ey, ez * ez));
  float v = wave_sum(dist1 + 0.3f * curv);
  if ((threadIdx.x & 63) == 0) atomicAdd(P.out, alpha * 0.5f * v);
}

extern "C" void kernel_launch(void* const* d_in, const int* in_sizes, int n_in,
                              void* d_out, int out_size, void* d_ws,
                              size_t ws_size, hipStream_t stream) {
  Params P;
  for (int s = 0; s < 4; ++s) {
    P.pc1[s] = (const float*)d_in[s];
    P.pc2[s] = (const float*)d_in[4 + s];
    P.fl[s]  = (const float*)d_in[8 + s];
  }
  char* ws = (char*)d_ws;
  P.cv2 = (float4*)ws;                               // 491520 B
  P.cvw = (float4*)(ws + 491520);                    // 491520 B
  P.k0  = (float*)(ws + 983040);                     // 6963200 B
  P.k1  = (float*)(ws + 7946240);                    // 6963200 B
  P.k3  = (float*)(ws + 14909440);                   // 3481600 B
  P.d2u = (uint*)(ws + 18391040);                    // 122880 B
  P.cnt = (uint*)(ws + 18513920);                    // 4 B
  P.keys = (float*)(ws + 983040);                    // fallback overlay
  P.out = (float*)d_out;

  if (ws_size >= 18513928) {
    k_init<<<dim3(120), dim3(256), 0, stream>>>(P);
    k_scan<<<dim3(2048), dim3(256), 0, stream>>>(P);
    k_epi_a<<<dim3(120), dim3(256), 0, stream>>>(P);
    k_epi_b<<<dim3(120), dim3(256), 0, stream>>>(P);
  } else {
    k_zero<<<dim3(1), dim3(1), 0, stream>>>(P.out);
    k_fused<<<dim3(4 * PB), dim3(BLOCK), 0, stream>>>(P);
    k_epi<<<dim3((2 * NTOT) / 256), dim3(256), 0, stream>>>(P);
  }
}

// Round 5
// 312.507 us; speedup vs baseline: 1.5242x; 1.5242x over previous
//
#include <hip/hip_runtime.h>
#include <math.h>

// PointPWC multi-scale loss. B=2, scales N={8192,4096,2048,1024}.
// Inputs (B,3,N) fp32 channel-major. Output: single fp32 scalar.
//
// R13 = R12 with the D-micro decode fixed for SGPR uniformity.
// R12 compile fail: D-micro derived (s,b) from wv -> base pointers
// wave-dependent -> "s" constraint unsatisfiable -> s_load got VGPRs.
// Now task id alone fixes (s,b); the 8 waves of a task split the
// within-batch wave-unit space (counts 4096/1024/256/64, all /8 exact).
//
// Schedule theory (R12): persistent 1024 8-wave blocks pop tasks
// heavy->light: A(340) B(340) C(340), then D as 1360 fine micro-tasks
// (8 waves x 64q x 256c, merge-free atomicMin; uint order == float order
// for d>=0). The splittable light pass backfills the drain tail that
// cost R10 ~100us (occupancy 64%). First task = blockIdx, counter
// pre-set to 1024 -> no pop burst. Scan cores = R10-proven scalar SMEM
// broadcast -> selection keys bit-identical. C/D epilogues in k_epi
// (R11-proven, absmax 0.0).

#define UNIT 1024
#define NTOT 15360
#define MASKC 0xFFFFE000u
#define NTASK 2380u   // 340 A + 340 B + 340 C + 1360 D-micro

typedef unsigned int uint;
typedef __attribute__((ext_vector_type(8))) float f8;

struct Params {
  const float* pc1[4];
  const float* pc2[4];
  const float* fl[4];
  float4* cv2;   // [B][NTOT]
  float4* cvw;   // [B][NTOT]
  float* keys;   // [5][B*NTOT] packed top-5 keys (pass C)
  uint* d2u;     // [B*NTOT] partial mins (pass D)
  uint* cnt;     // task queue counter
  float* out;
};

// ---------- helpers (R10-proven, bit-identical math) ----------

__device__ __forceinline__ float wave_sum(float v) {
  #pragma unroll
  for (int o = 32; o; o >>= 1) v += __shfl_down(v, o, 64);
  return v;
}

template <int K>
__device__ __forceinline__ void key_insert(float (&kd)[K], float kf) {
  #pragma unroll
  for (int m = K - 1; m >= 1; --m)
    kd[m] = __builtin_amdgcn_fmed3f(kf, kd[m - 1], kd[m]);
  kd[0] = fminf(kd[0], kf);
}

template <int K>
__device__ __forceinline__ void merge_pair(float (&a)[K], const float (&b)[K]) {
  #pragma unroll
  for (int m = 0; m < K; ++m) key_insert<K>(a, b[m]);
}

__device__ __forceinline__ float pack_key_u(float d, uint iw) {
  return __uint_as_float((__float_as_uint(d) & MASKC) | iw);
}

// Wave-uniform broadcast of 8 candidates (3 planes) into SGPRs. Loads +
// waitcnt fused in ONE asm block (SMEM completes out-of-order). Pointers
// must be block-uniform (or provably lane-uniform) for "s" to hold.
__device__ __forceinline__ void sload3(const float* px, const float* py,
                                       const float* pz, int boff,
                                       f8& x, f8& y, f8& z) {
  asm volatile(
      "s_load_dwordx8 %0, %3, %6\n\t"
      "s_load_dwordx8 %1, %4, %6\n\t"
      "s_load_dwordx8 %2, %5, %6\n\t"
      "s_waitcnt lgkmcnt(0)"
      : "=&s"(x), "=&s"(y), "=&s"(z)
      : "s"(px), "s"(py), "s"(pz), "s"(boff));
}

__device__ __forceinline__ void sload6(const float* px, const float* py,
                                       const float* pz, const float* fx,
                                       const float* fy, const float* fz,
                                       int boff, f8& x, f8& y, f8& z,
                                       f8& u, f8& v, f8& w) {
  asm volatile(
      "s_load_dwordx8 %0, %6, %12\n\t"
      "s_load_dwordx8 %1, %7, %12\n\t"
      "s_load_dwordx8 %2, %8, %12\n\t"
      "s_load_dwordx8 %3, %9, %12\n\t"
      "s_load_dwordx8 %4, %10, %12\n\t"
      "s_load_dwordx8 %5, %11, %12\n\t"
      "s_waitcnt lgkmcnt(0)"
      : "=&s"(x), "=&s"(y), "=&s"(z), "=&s"(u), "=&s"(v), "=&s"(w)
      : "s"(px), "s"(py), "s"(pz), "s"(fx), "s"(fy), "s"(fz), "s"(boff));
}

// Top-K scan over [lo, lo+UNIT); candidates from SGPRs. Two chains.
template <int K>
__device__ void scan_k(const float* px, const float* py, const float* pz,
                       int lo, float ax, float ay, float az,
                       float (&a)[K], float (&b)[K]) {
  #pragma unroll 1
  for (int c0 = 0; c0 < UNIT; c0 += 8) {
    f8 xs, ys, zs;
    sload3(px, py, pz, (lo + c0) * 4, xs, ys, zs);
    #pragma unroll
    for (int t = 0; t < 8; t += 2) {
      float dxa = xs[t] - ax, dya = ys[t] - ay, dza = zs[t] - az;
      float dA = fmaf(dxa, dxa, fmaf(dya, dya, dza * dza));
      float dxb = xs[t + 1] - ax, dyb = ys[t + 1] - ay, dzb = zs[t + 1] - az;
      float dB = fmaf(dxb, dxb, fmaf(dyb, dyb, dzb * dzb));
      key_insert<K>(a, pack_key_u(dA, (uint)(lo + c0 + t)));
      key_insert<K>(b, pack_key_u(dB, (uint)(lo + c0 + t + 1)));
    }
  }
}

// Pass-D scan over 256 candidates: candidates = p1+fl (exact R10
// rounding), running min only.
__device__ void scan_w256(const float* px, const float* py, const float* pz,
                          const float* fx, const float* fy, const float* fz,
                          int lo, float ax, float ay, float az,
                          float& a0, float& b0) {
  #pragma unroll 1
  for (int c0 = 0; c0 < 256; c0 += 8) {
    f8 xs, ys, zs, us, vs, ws;
    sload6(px, py, pz, fx, fy, fz, (lo + c0) * 4, xs, ys, zs, us, vs, ws);
    #pragma unroll
    for (int t = 0; t < 8; t += 2) {
      float cxa = xs[t] + us[t], cya = ys[t] + vs[t], cza = zs[t] + ws[t];
      float dxa = cxa - ax, dya = cya - ay, dza = cza - az;
      float dA = fmaf(dxa, dxa, fmaf(dya, dya, dza * dza));
      float cxb = xs[t + 1] + us[t + 1], cyb = ys[t + 1] + vs[t + 1],
            czb = zs[t + 1] + ws[t + 1];
      float dxb = cxb - ax, dyb = cyb - ay, dzb = czb - az;
      float dB = fmaf(dxb, dxb, fmaf(dyb, dyb, dzb * dzb));
      a0 = fminf(a0, dA);
      b0 = fminf(b0, dB);
    }
  }
}

// r in [0,340) -> scale s, batch b, query-group base i0, candidate lo.
// (s, b, i0-per-wave rule: only i0/lo depend on wv; s,b block-uniform.)
__device__ __forceinline__ void decode(int r, int wv, int& s, int& b,
                                       int& i0, int& lo, int& N, int& cpw,
                                       int& off, float& alpha) {
  int rr;
  if (r < 256)      { s = 0; rr = r; }
  else if (r < 320) { s = 1; rr = r - 256; }
  else if (r < 336) { s = 2; rr = r - 320; }
  else              { s = 3; rr = r - 336; }
  N = 8192 >> s;
  cpw = 8 >> s;
  int perb = 128 >> (2 * s);
  b = rr >> (7 - 2 * s);
  int chunk = rr & (perb - 1);
  int qg = (chunk << s) + (wv >> (3 - s));
  i0 = qg << 6;
  lo = (wv & (cpw - 1)) << 10;
  off = 16384 - (16384 >> s);
  alpha = 0.02f * (float)(1 << s);
}

// Stage per-thread list; group leader (wave with cr==0) merges its
// qgroup's cpw lists. Returns true for leader threads.
template <int K>
__device__ __forceinline__ bool merge_group(float (&a)[K], float* sm,
                                            int tid, int cpw) {
  const int STR = K | 1;   // odd stride: 2-way bank aliasing only (free)
  int q = tid & 63, wv = tid >> 6;
  #pragma unroll
  for (int m = 0; m < K; ++m) sm[(wv * 64 + q) * STR + m] = a[m];
  __syncthreads();
  if (wv & (cpw - 1)) return false;
  for (int w = wv + 1; w < wv + cpw; ++w)
    #pragma unroll
    for (int m = 0; m < K; ++m)
      key_insert<K>(a, sm[(w * 64 + q) * STR + m]);
  return true;
}

// ---------- kernels ----------

__global__ __launch_bounds__(256) void k_init(Params P) {
  int t = blockIdx.x * 256 + threadIdx.x;
  if (t == 0) { P.out[0] = 0.f; *P.cnt = 1024u; }   // first tasks static
  if (t < 2 * NTOT) P.d2u[t] = 0x7F7FFFFFu;         // FLT_MAX bits
}

// Persistent blocks; task t: [0,340) A, [340,680) B, [680,1020) C,
// [1020,2380) D-micro. D-micro decode: (s,b) from t ONLY (SGPR-uniform
// base pointers); waves split within-batch wave-units u = ti*8 + wv,
// qg = u / (32>>s), rg = u % (32>>s)  (counts 4096/1024/256/64, /8 exact).
__global__ __launch_bounds__(512, 8) void k_work(Params P) {
  __shared__ float sm[8 * 64 * 11];   // 22.5 KB merge staging
  __shared__ uint ts;
  int tid = threadIdx.x, q = tid & 63, wv = tid >> 6;

  uint t = blockIdx.x;                // static first task, no pop burst
  while (t < NTASK) {
    if (t < 1020u) {
      int pass = (int)t / 340, r = (int)t % 340;
      int s, b, i0, lo, N, cpw, off; float alpha;
      decode(r, wv, s, b, i0, lo, N, cpw, off, alpha);
      int i = i0 + q;
      int lo_u = __builtin_amdgcn_readfirstlane(lo);

      if (pass == 0) {            // A: p2 self top-10 -> cv2
        const float* p2 = P.pc2[s] + b * 3 * N;
        float ax = p2[i], ay = p2[N + i], az = p2[2 * N + i];
        float a[10], bb[10];
        #pragma unroll
        for (int m = 0; m < 10; ++m) { a[m] = 3.0e38f; bb[m] = 3.0e38f; }
        scan_k<10>(p2, p2 + N, p2 + 2 * N, lo_u, ax, ay, az, a, bb);
        merge_pair<10>(a, bb);
        if (merge_group<10>(a, sm, tid, cpw)) {
          float sx = 0.f, sy = 0.f, sz = 0.f;
          #pragma unroll
          for (int m = 0; m < 10; ++m) {
            int j = (int)(__float_as_uint(a[m]) & 0x1FFFu);
            sx += p2[j]; sy += p2[N + j]; sz += p2[2 * N + j];
          }
          const float inv9 = 1.f / 9.f;
          P.cv2[b * NTOT + off + i] = make_float4((sx - 10.f * ax) * inv9,
                                                  (sy - 10.f * ay) * inv9,
                                                  (sz - 10.f * az) * inv9,
                                                  0.f);
        }
      } else if (pass == 1) {     // B: p1 self top-10 -> cvw + smooth
        const float* p1 = P.pc1[s] + b * 3 * N;
        const float* fl = P.fl[s] + b * 3 * N;
        float ax = p1[i], ay = p1[N + i], az = p1[2 * N + i];
        float a[10], bb[10];
        #pragma unroll
        for (int m = 0; m < 10; ++m) { a[m] = 3.0e38f; bb[m] = 3.0e38f; }
        scan_k<10>(p1, p1 + N, p1 + 2 * N, lo_u, ax, ay, az, a, bb);
        merge_pair<10>(a, bb);
        if (merge_group<10>(a, sm, tid, cpw)) {
          float fix = fl[i], fiy = fl[N + i], fiz = fl[2 * N + i];
          float wix = ax + fix, wiy = ay + fiy, wiz = az + fiz;
          float sx = 0.f, sy = 0.f, sz = 0.f, smooth = 0.f;
          float dmax = -1.f, worst = 0.f;
          #pragma unroll
          for (int m = 0; m < 10; ++m) {
            int j = (int)(__float_as_uint(a[m]) & 0x1FFFu);
            float px = p1[j], py = p1[N + j], pz = p1[2 * N + j];
            float flx = fl[j], fly = fl[N + j], flz = fl[2 * N + j];
            sx += px + flx; sy += py + fly; sz += pz + flz;
            float ddx = px - ax, ddy = py - ay, ddz = pz - az;
            float d = fmaf(ddx, ddx, fmaf(ddy, ddy, ddz * ddz));  // exact
            float gx = flx - fix, gy = fly - fiy, gz = flz - fiz;
            float term = sqrtf(fmaf(gx, gx, fmaf(gy, gy, gz * gz)));
            smooth += term;
            if (d > dmax) { dmax = d; worst = term; }  // drop farthest (k9)
          }
          smooth -= worst;
          const float inv9 = 1.f / 9.f;
          P.cvw[b * NTOT + off + i] = make_float4((sx - 10.f * wix) * inv9,
                                                  (sy - 10.f * wiy) * inv9,
                                                  (sz - 10.f * wiz) * inv9,
                                                  0.f);
          float ssum = wave_sum(smooth * (1.f / 8.f));
          if (q == 0) atomicAdd(P.out, alpha * 0.5f * ssum);
        }
      } else {                    // C: warp -> p2 top-5 -> packed keys
        const float* p1 = P.pc1[s] + b * 3 * N;
        const float* fl = P.fl[s] + b * 3 * N;
        const float* p2 = P.pc2[s] + b * 3 * N;
        float ax = p1[i] + fl[i], ay = p1[N + i] + fl[N + i],
              az = p1[2 * N + i] + fl[2 * N + i];
        float a[5], bb[5];
        #pragma unroll
        for (int m = 0; m < 5; ++m) { a[m] = 3.0e38f; bb[m] = 3.0e38f; }
        scan_k<5>(p2, p2 + N, p2 + 2 * N, lo_u, ax, ay, az, a, bb);
        merge_pair<5>(a, bb);
        if (merge_group<5>(a, sm, tid, cpw)) {
          #pragma unroll
          for (int m = 0; m < 5; ++m)
            P.keys[m * (2 * NTOT) + b * NTOT + off + i] = a[m];
        }
      }
    } else {                      // D-micro: p2 -> warp min, atomicMin
      int dm = (int)(t - 1020u);
      int s, tb;
      if (dm < 1024)      { s = 0; tb = dm; }
      else if (dm < 1280) { s = 1; tb = dm - 1024; }
      else if (dm < 1344) { s = 2; tb = dm - 1280; }
      else                { s = 3; tb = dm - 1344; }
      int N = 8192 >> s;
      int tpb = 512 >> (2 * s);            // tasks per batch
      int b = tb >> (9 - 2 * s);           // tb / tpb
      int ti = tb & (tpb - 1);
      int u = ti * 8 + wv;                 // wave-unit within batch
      int rpq = 32 >> s;                   // 256-ranges per qgroup
      int qg = u >> (5 - s);               // u / rpq
      int rg = u & (rpq - 1);
      int i = qg * 64 + q, lo = rg * 256;
      int off = 16384 - (16384 >> s);
      const float* p1 = P.pc1[s] + b * 3 * N;   // block-uniform
      const float* fl = P.fl[s] + b * 3 * N;
      const float* p2 = P.pc2[s] + b * 3 * N;
      float ax = p2[i], ay = p2[N + i], az = p2[2 * N + i];
      float a0 = 3.0e38f, b0 = 3.0e38f;
      int lo_u = __builtin_amdgcn_readfirstlane(lo);
      scan_w256(p1, p1 + N, p1 + 2 * N, fl, fl + N, fl + 2 * N,
                lo_u, ax, ay, az, a0, b0);
      atomicMin(P.d2u + b * NTOT + off + i, __float_as_uint(fminf(a0, b0)));
    }
    __syncthreads();              // sm + ts reuse safety
    if (tid == 0) ts = atomicAdd(P.cnt, 1u);
    __syncthreads();
    t = ts;
  }
}

// Epilogue: C top-5 -> dist1 + inverse-distance cv2 interp -> curvature;
// plus D partial-min sum. 30720 threads.
__global__ __launch_bounds__(256) void k_epi(Params P) {
  int t = blockIdx.x * 256 + threadIdx.x;   // [0, 2*NTOT)
  int b = t >= NTOT;
  int r = t - b * NTOT;
  int s, i;
  if (r < 8192)       { s = 0; i = r; }
  else if (r < 12288) { s = 1; i = r - 8192; }
  else if (r < 14336) { s = 2; i = r - 12288; }
  else                { s = 3; i = r - 14336; }
  int N = 8192 >> s;
  int off = 16384 - (16384 >> s);
  float alpha = 0.02f * (float)(1 << s);
  const float* p1 = P.pc1[s] + b * 3 * N;
  const float* fl = P.fl[s] + b * 3 * N;
  const float* p2 = P.pc2[s] + b * 3 * N;
  float ax = p1[i] + fl[i], ay = p1[N + i] + fl[N + i],
        az = p1[2 * N + i] + fl[2 * N + i];
  float dist1 = 3.0e38f, wsum = 0.f, ix = 0.f, iy = 0.f, iz = 0.f;
  #pragma unroll
  for (int m = 0; m < 5; ++m) {
    uint key = __float_as_uint(P.keys[m * (2 * NTOT) + b * NTOT + off + i]);
    int j = (int)(key & 0x1FFFu);
    float px = p2[j], py = p2[N + j], pz = p2[2 * N + j];
    float ddx = px - ax, ddy = py - ay, ddz = pz - az;
    float d = fmaf(ddx, ddx, fmaf(ddy, ddy, ddz * ddz));  // exact
    dist1 = fminf(dist1, d);
    float w = 1.f / (d + 1e-8f);
    wsum += w;
    float4 cv = P.cv2[b * NTOT + off + j];
    ix += w * cv.x; iy += w * cv.y; iz += w * cv.z;
  }
  float inv = 1.f / wsum;
  ix *= inv; iy *= inv; iz *= inv;
  float4 cw = P.cvw[b * NTOT + off + i];
  float ex = ix - cw.x, ey = iy - cw.y, ez = iz - cw.z;
  float curv = fmaf(ex, ex, fmaf(ey, ey, ez * ez));
  float csum = wave_sum(dist1 + 0.3f * curv);
  float msum = wave_sum(__uint_as_float(P.d2u[t]));
  if ((threadIdx.x & 63) == 0) {
    atomicAdd(P.out, alpha * 0.5f * csum);
    atomicAdd(P.out, alpha * 0.5f * msum);
  }
}

extern "C" void kernel_launch(void* const* d_in, const int* in_sizes, int n_in,
                              void* d_out, int out_size, void* d_ws,
                              size_t ws_size, hipStream_t stream) {
  Params P;
  for (int s = 0; s < 4; ++s) {
    P.pc1[s] = (const float*)d_in[s];
    P.pc2[s] = (const float*)d_in[4 + s];
    P.fl[s]  = (const float*)d_in[8 + s];
  }
  char* ws = (char*)d_ws;
  P.cv2  = (float4*)ws;                    // 491520 B
  P.cvw  = (float4*)(ws + 491520);         // 491520 B
  P.keys = (float*)(ws + 983040);          // 614400 B
  P.d2u  = (uint*)(ws + 1597440);          // 122880 B
  P.cnt  = (uint*)(ws + 1720320);          // 4 B  (ws_size >= 18.5MB proven R11)
  P.out  = (float*)d_out;

  k_init<<<dim3(120), dim3(256), 0, stream>>>(P);
  k_work<<<dim3(1024), dim3(512), 0, stream>>>(P);
  k_epi<<<dim3(120), dim3(256), 0, stream>>>(P);
}

// Round 6
// 301.907 us; speedup vs baseline: 1.5778x; 1.0351x over previous
//
#include <hip/hip_runtime.h>
#include <math.h>

// PointPWC multi-scale loss. B=2, scales N={8192,4096,2048,1024}.
// Inputs (B,3,N) fp32 channel-major. Output: single fp32 scalar.
//
// R14: attack per-candidate cost (R13 exonerated scheduling: occupancy
// 64->70 but only 267->256us). Measured 56.4 SIMD-cyc per 64q-candidate
// unit vs 29.5 ideal VALU -> ~1 unhidden SMEM round-trip per 8-cand
// chunk (scalar K$ is shared; lgkmcnt(0) must drain fully since SMEM
// completes out-of-order). Changes:
//  1. s_load_dwordx16 chunks (16 cand): same bytes, half the SMEM
//     transactions and half the stall frequency. Same proven single-asm
//     load+wait pattern.
//  2. warp = p1+fl precomputed in k_init (flat add, same rounding ->
//     bit-identical). Pass D: sload6+10 VALU/cand -> sload3+7; pass C
//     queries read warp.
//  3. Schedule unchanged from R13 (persistent 1024 blocks, A/B/C heavy
//     tasks then 1360 fine D-micro fillers, atomicMin merge).
// Selection keys bit-identical throughout -> absmax must stay 0.

#define UNIT 1024
#define NTOT 15360
#define MASKC 0xFFFFE000u
#define NTASK 2380u   // 340 A + 340 B + 340 C + 1360 D-micro

typedef unsigned int uint;
typedef __attribute__((ext_vector_type(16))) float f16v;

struct Params {
  const float* pc1[4];
  const float* pc2[4];
  const float* fl[4];
  float4* cv2;   // [B][NTOT]
  float4* cvw;   // [B][NTOT]
  float* keys;   // [5][B*NTOT] packed top-5 keys (pass C)
  uint* d2u;     // [B*NTOT] partial mins (pass D)
  uint* cnt;     // task queue counter
  float* warp;   // per-scale [B][3][N] warped p1 (= p1+fl)
  float* out;
};

// ---------- helpers ----------

__device__ __forceinline__ float wave_sum(float v) {
  #pragma unroll
  for (int o = 32; o; o >>= 1) v += __shfl_down(v, o, 64);
  return v;
}

template <int K>
__device__ __forceinline__ void key_insert(float (&kd)[K], float kf) {
  #pragma unroll
  for (int m = K - 1; m >= 1; --m)
    kd[m] = __builtin_amdgcn_fmed3f(kf, kd[m - 1], kd[m]);
  kd[0] = fminf(kd[0], kf);
}

template <int K>
__device__ __forceinline__ void merge_pair(float (&a)[K], const float (&b)[K]) {
  #pragma unroll
  for (int m = 0; m < K; ++m) key_insert<K>(a, b[m]);
}

__device__ __forceinline__ float pack_key_u(float d, uint iw) {
  return __uint_as_float((__float_as_uint(d) & MASKC) | iw);
}

// Wave-uniform broadcast of 16 candidates (3 planes) into SGPRs. Loads +
// waitcnt fused in ONE asm block (SMEM completes out-of-order; counted
// lgkm waits are unsafe; split issue/wait risks spills of in-flight
// regs). Pointers must be block-uniform for "s" to hold.
__device__ __forceinline__ void sload3x16(const float* px, const float* py,
                                          const float* pz, int boff,
                                          f16v& x, f16v& y, f16v& z) {
  asm volatile(
      "s_load_dwordx16 %0, %3, %6\n\t"
      "s_load_dwordx16 %1, %4, %6\n\t"
      "s_load_dwordx16 %2, %5, %6\n\t"
      "s_waitcnt lgkmcnt(0)"
      : "=&s"(x), "=&s"(y), "=&s"(z)
      : "s"(px), "s"(py), "s"(pz), "s"(boff));
}

// Top-K scan over [lo, lo+UNIT); candidates from SGPRs. Two chains.
template <int K>
__device__ void scan_k(const float* px, const float* py, const float* pz,
                       int lo, float ax, float ay, float az,
                       float (&a)[K], float (&b)[K]) {
  #pragma unroll 1
  for (int c0 = 0; c0 < UNIT; c0 += 16) {
    f16v xs, ys, zs;
    sload3x16(px, py, pz, (lo + c0) * 4, xs, ys, zs);
    #pragma unroll
    for (int t = 0; t < 16; t += 2) {
      float dxa = xs[t] - ax, dya = ys[t] - ay, dza = zs[t] - az;
      float dA = fmaf(dxa, dxa, fmaf(dya, dya, dza * dza));
      float dxb = xs[t + 1] - ax, dyb = ys[t + 1] - ay, dzb = zs[t + 1] - az;
      float dB = fmaf(dxb, dxb, fmaf(dyb, dyb, dzb * dzb));
      key_insert<K>(a, pack_key_u(dA, (uint)(lo + c0 + t)));
      key_insert<K>(b, pack_key_u(dB, (uint)(lo + c0 + t + 1)));
    }
  }
}

// Min-only scan over [lo, lo+len): candidates from SGPRs (pass D uses
// precomputed warp -> 7 VALU/candidate).
__device__ void scan_m(const float* px, const float* py, const float* pz,
                       int lo, int len, float ax, float ay, float az,
                       float& a0, float& b0) {
  #pragma unroll 1
  for (int c0 = 0; c0 < len; c0 += 16) {
    f16v xs, ys, zs;
    sload3x16(px, py, pz, (lo + c0) * 4, xs, ys, zs);
    #pragma unroll
    for (int t = 0; t < 16; t += 2) {
      float dxa = xs[t] - ax, dya = ys[t] - ay, dza = zs[t] - az;
      float dA = fmaf(dxa, dxa, fmaf(dya, dya, dza * dza));
      float dxb = xs[t + 1] - ax, dyb = ys[t + 1] - ay, dzb = zs[t + 1] - az;
      float dB = fmaf(dxb, dxb, fmaf(dyb, dyb, dzb * dzb));
      a0 = fminf(a0, dA);
      b0 = fminf(b0, dB);
    }
  }
}

// r in [0,340) -> scale s, batch b, query-group base i0, candidate lo.
// Only i0/lo depend on wv; s,b are block-uniform.
__device__ __forceinline__ void decode(int r, int wv, int& s, int& b,
                                       int& i0, int& lo, int& N, int& cpw,
                                       int& off, float& alpha) {
  int rr;
  if (r < 256)      { s = 0; rr = r; }
  else if (r < 320) { s = 1; rr = r - 256; }
  else if (r < 336) { s = 2; rr = r - 320; }
  else              { s = 3; rr = r - 336; }
  N = 8192 >> s;
  cpw = 8 >> s;
  int perb = 128 >> (2 * s);
  b = rr >> (7 - 2 * s);
  int chunk = rr & (perb - 1);
  int qg = (chunk << s) + (wv >> (3 - s));
  i0 = qg << 6;
  lo = (wv & (cpw - 1)) << 10;
  off = 16384 - (16384 >> s);
  alpha = 0.02f * (float)(1 << s);
}

// Stage per-thread list; group leader (wave with cr==0) merges its
// qgroup's cpw lists. Returns true for leader threads.
template <int K>
__device__ __forceinline__ bool merge_group(float (&a)[K], float* sm,
                                            int tid, int cpw) {
  const int STR = K | 1;   // odd stride: 2-way bank aliasing only (free)
  int q = tid & 63, wv = tid >> 6;
  #pragma unroll
  for (int m = 0; m < K; ++m) sm[(wv * 64 + q) * STR + m] = a[m];
  __syncthreads();
  if (wv & (cpw - 1)) return false;
  for (int w = wv + 1; w < wv + cpw; ++w)
    #pragma unroll
    for (int m = 0; m < K; ++m)
      key_insert<K>(a, sm[(w * 64 + q) * STR + m]);
  return true;
}

// ---------- kernels ----------

// Init scalars/d2u AND precompute warp = p1+fl. Both are [b][3][N] flat
// per scale, so warp[base6(s)+r] = pc1[s][r] + fl[s][r] with no decode.
// base6 = 6*off(s) = {0, 49152, 73728, 86016}; total 92160 elems.
__global__ __launch_bounds__(256) void k_init(Params P) {
  int t = blockIdx.x * 256 + threadIdx.x;
  if (t == 0) { P.out[0] = 0.f; *P.cnt = 1024u; }   // first tasks static
  if (t < 2 * NTOT) P.d2u[t] = 0x7F7FFFFFu;         // FLT_MAX bits
  int s, r;
  if (t < 49152)      { s = 0; r = t; }
  else if (t < 73728) { s = 1; r = t - 49152; }
  else if (t < 86016) { s = 2; r = t - 73728; }
  else if (t < 92160) { s = 3; r = t - 86016; }
  else return;
  int base6 = (s == 0) ? 0 : (s == 1) ? 49152 : (s == 2) ? 73728 : 86016;
  P.warp[base6 + r] = P.pc1[s][r] + P.fl[s][r];     // same rounding as R13
}

// Persistent blocks; task t: [0,340) A, [340,680) B, [680,1020) C,
// [1020,2380) D-micro. D-micro: (s,b) from t ONLY (SGPR-uniform base
// pointers); 8 waves split within-batch wave-units u = ti*8 + wv.
__global__ __launch_bounds__(512, 8) void k_work(Params P) {
  __shared__ float sm[8 * 64 * 11];   // 22.5 KB merge staging
  __shared__ uint ts;
  int tid = threadIdx.x, q = tid & 63, wv = tid >> 6;

  uint t = blockIdx.x;                // static first task, no pop burst
  while (t < NTASK) {
    if (t < 1020u) {
      int pass = (int)t / 340, r = (int)t % 340;
      int s, b, i0, lo, N, cpw, off; float alpha;
      decode(r, wv, s, b, i0, lo, N, cpw, off, alpha);
      int i = i0 + q;
      int lo_u = __builtin_amdgcn_readfirstlane(lo);

      if (pass == 0) {            // A: p2 self top-10 -> cv2
        const float* p2 = P.pc2[s] + b * 3 * N;
        float ax = p2[i], ay = p2[N + i], az = p2[2 * N + i];
        float a[10], bb[10];
        #pragma unroll
        for (int m = 0; m < 10; ++m) { a[m] = 3.0e38f; bb[m] = 3.0e38f; }
        scan_k<10>(p2, p2 + N, p2 + 2 * N, lo_u, ax, ay, az, a, bb);
        merge_pair<10>(a, bb);
        if (merge_group<10>(a, sm, tid, cpw)) {
          float sx = 0.f, sy = 0.f, sz = 0.f;
          #pragma unroll
          for (int m = 0; m < 10; ++m) {
            int j = (int)(__float_as_uint(a[m]) & 0x1FFFu);
            sx += p2[j]; sy += p2[N + j]; sz += p2[2 * N + j];
          }
          const float inv9 = 1.f / 9.f;
          P.cv2[b * NTOT + off + i] = make_float4((sx - 10.f * ax) * inv9,
                                                  (sy - 10.f * ay) * inv9,
                                                  (sz - 10.f * az) * inv9,
                                                  0.f);
        }
      } else if (pass == 1) {     // B: p1 self top-10 -> cvw + smooth
        const float* p1 = P.pc1[s] + b * 3 * N;
        const float* fl = P.fl[s] + b * 3 * N;
        float ax = p1[i], ay = p1[N + i], az = p1[2 * N + i];
        float a[10], bb[10];
        #pragma unroll
        for (int m = 0; m < 10; ++m) { a[m] = 3.0e38f; bb[m] = 3.0e38f; }
        scan_k<10>(p1, p1 + N, p1 + 2 * N, lo_u, ax, ay, az, a, bb);
        merge_pair<10>(a, bb);
        if (merge_group<10>(a, sm, tid, cpw)) {
          float fix = fl[i], fiy = fl[N + i], fiz = fl[2 * N + i];
          float wix = ax + fix, wiy = ay + fiy, wiz = az + fiz;
          float sx = 0.f, sy = 0.f, sz = 0.f, smooth = 0.f;
          float dmax = -1.f, worst = 0.f;
          #pragma unroll
          for (int m = 0; m < 10; ++m) {
            int j = (int)(__float_as_uint(a[m]) & 0x1FFFu);
            float px = p1[j], py = p1[N + j], pz = p1[2 * N + j];
            float flx = fl[j], fly = fl[N + j], flz = fl[2 * N + j];
            sx += px + flx; sy += py + fly; sz += pz + flz;
            float ddx = px - ax, ddy = py - ay, ddz = pz - az;
            float d = fmaf(ddx, ddx, fmaf(ddy, ddy, ddz * ddz));  // exact
            float gx = flx - fix, gy = fly - fiy, gz = flz - fiz;
            float term = sqrtf(fmaf(gx, gx, fmaf(gy, gy, gz * gz)));
            smooth += term;
            if (d > dmax) { dmax = d; worst = term; }  // drop farthest (k9)
          }
          smooth -= worst;
          const float inv9 = 1.f / 9.f;
          P.cvw[b * NTOT + off + i] = make_float4((sx - 10.f * wix) * inv9,
                                                  (sy - 10.f * wiy) * inv9,
                                                  (sz - 10.f * wiz) * inv9,
                                                  0.f);
          float ssum = wave_sum(smooth * (1.f / 8.f));
          if (q == 0) atomicAdd(P.out, alpha * 0.5f * ssum);
        }
      } else {                    // C: warp -> p2 top-5 -> packed keys
        int base6 = (s == 0) ? 0 : (s == 1) ? 49152 : (s == 2) ? 73728
                                                               : 86016;
        const float* wq = P.warp + base6 + b * 3 * N;
        const float* p2 = P.pc2[s] + b * 3 * N;
        float ax = wq[i], ay = wq[N + i], az = wq[2 * N + i];  // == p1+fl
        float a[5], bb[5];
        #pragma unroll
        for (int m = 0; m < 5; ++m) { a[m] = 3.0e38f; bb[m] = 3.0e38f; }
        scan_k<5>(p2, p2 + N, p2 + 2 * N, lo_u, ax, ay, az, a, bb);
        merge_pair<5>(a, bb);
        if (merge_group<5>(a, sm, tid, cpw)) {
          #pragma unroll
          for (int m = 0; m < 5; ++m)
            P.keys[m * (2 * NTOT) + b * NTOT + off + i] = a[m];
        }
      }
    } else {                      // D-micro: p2 -> warp min, atomicMin
      int dm = (int)(t - 1020u);
      int s, tb;
      if (dm < 1024)      { s = 0; tb = dm; }
      else if (dm < 1280) { s = 1; tb = dm - 1024; }
      else if (dm < 1344) { s = 2; tb = dm - 1280; }
      else                { s = 3; tb = dm - 1344; }
      int N = 8192 >> s;
      int tpb = 512 >> (2 * s);            // tasks per batch
      int b = tb >> (9 - 2 * s);           // tb / tpb
      int ti = tb & (tpb - 1);
      int u = ti * 8 + wv;                 // wave-unit within batch
      int rpq = 32 >> s;                   // 256-ranges per qgroup
      int qg = u >> (5 - s);               // u / rpq
      int rg = u & (rpq - 1);
      int i = qg * 64 + q, lo = rg * 256;
      int off = 16384 - (16384 >> s);
      int base6 = (s == 0) ? 0 : (s == 1) ? 49152 : (s == 2) ? 73728
                                                             : 86016;
      const float* wc = P.warp + base6 + b * 3 * N;  // block-uniform
      const float* p2 = P.pc2[s] + b * 3 * N;
      float ax = p2[i], ay = p2[N + i], az = p2[2 * N + i];
      float a0 = 3.0e38f, b0 = 3.0e38f;
      int lo_u = __builtin_amdgcn_readfirstlane(lo);
      scan_m(wc, wc + N, wc + 2 * N, lo_u, 256, ax, ay, az, a0, b0);
      atomicMin(P.d2u + b * NTOT + off + i, __float_as_uint(fminf(a0, b0)));
    }
    __syncthreads();              // sm + ts reuse safety
    if (tid == 0) ts = atomicAdd(P.cnt, 1u);
    __syncthreads();
    t = ts;
  }
}

// Epilogue: C top-5 -> dist1 + inverse-distance cv2 interp -> curvature;
// plus D partial-min sum. 30720 threads.
__global__ __launch_bounds__(256) void k_epi(Params P) {
  int t = blockIdx.x * 256 + threadIdx.x;   // [0, 2*NTOT)
  int b = t >= NTOT;
  int r = t - b * NTOT;
  int s, i;
  if (r < 8192)       { s = 0; i = r; }
  else if (r < 12288) { s = 1; i = r - 8192; }
  else if (r < 14336) { s = 2; i = r - 12288; }
  else                { s = 3; i = r - 14336; }
  int N = 8192 >> s;
  int off = 16384 - (16384 >> s);
  float alpha = 0.02f * (float)(1 << s);
  const float* p1 = P.pc1[s] + b * 3 * N;
  const float* fl = P.fl[s] + b * 3 * N;
  const float* p2 = P.pc2[s] + b * 3 * N;
  float ax = p1[i] + fl[i], ay = p1[N + i] + fl[N + i],
        az = p1[2 * N + i] + fl[2 * N + i];
  float dist1 = 3.0e38f, wsum = 0.f, ix = 0.f, iy = 0.f, iz = 0.f;
  #pragma unroll
  for (int m = 0; m < 5; ++m) {
    uint key = __float_as_uint(P.keys[m * (2 * NTOT) + b * NTOT + off + i]);
    int j = (int)(key & 0x1FFFu);
    float px = p2[j], py = p2[N + j], pz = p2[2 * N + j];
    float ddx = px - ax, ddy = py - ay, ddz = pz - az;
    float d = fmaf(ddx, ddx, fmaf(ddy, ddy, ddz * ddz));  // exact
    dist1 = fminf(dist1, d);
    float w = 1.f / (d + 1e-8f);
    wsum += w;
    float4 cv = P.cv2[b * NTOT + off + j];
    ix += w * cv.x; iy += w * cv.y; iz += w * cv.z;
  }
  float inv = 1.f / wsum;
  ix *= inv; iy *= inv; iz *= inv;
  float4 cw = P.cvw[b * NTOT + off + i];
  float ex = ix - cw.x, ey = iy - cw.y, ez = iz - cw.z;
  float curv = fmaf(ex, ex, fmaf(ey, ey, ez * ez));
  float csum = wave_sum(dist1 + 0.3f * curv);
  float msum = wave_sum(__uint_as_float(P.d2u[t]));
  if ((threadIdx.x & 63) == 0) {
    atomicAdd(P.out, alpha * 0.5f * csum);
    atomicAdd(P.out, alpha * 0.5f * msum);
  }
}

extern "C" void kernel_launch(void* const* d_in, const int* in_sizes, int n_in,
                              void* d_out, int out_size, void* d_ws,
                              size_t ws_size, hipStream_t stream) {
  Params P;
  for (int s = 0; s < 4; ++s) {
    P.pc1[s] = (const float*)d_in[s];
    P.pc2[s] = (const float*)d_in[4 + s];
    P.fl[s]  = (const float*)d_in[8 + s];
  }
  char* ws = (char*)d_ws;
  P.cv2  = (float4*)ws;                    // 491520 B
  P.cvw  = (float4*)(ws + 491520);         // 491520 B
  P.keys = (float*)(ws + 983040);          // 614400 B
  P.d2u  = (uint*)(ws + 1597440);          // 122880 B
  P.cnt  = (uint*)(ws + 1720320);          // 64 B
  P.warp = (float*)(ws + 1720384);         // 368640 B (total 2089024)
  P.out  = (float*)d_out;

  k_init<<<dim3(360), dim3(256), 0, stream>>>(P);
  k_work<<<dim3(1024), dim3(512), 0, stream>>>(P);
  k_epi<<<dim3(120), dim3(256), 0, stream>>>(P);
}